// Round 6
// baseline (159.871 us; speedup 1.0000x reference)
//
#include <hip/hip_runtime.h>
#include <math.h>

// Maxwell IIR scan. stress[t] = a*stress[t-1] + E*(s[t]-s[t-1]), a=exp(-dt*E/eta),
// stress[0] = E*s[0] + eta*r[0].
//
// Reformulation: y[t]=stress[t]-E*s[t] => y[t]=a*y[t-1]+c*s[t-1], c=E*(a-1),
// so  stress[t] = E*s[t] + c*Z[t-1] + a^t*eta*r0,  Z = plain scan of s.
//
// Warm-up truncation (a^1024~3.6e-5) instead of inter-block carries (G16-safe).
// R3: DS-bpermute chains = latency wall (45us). R4: contig-per-lane layout broke
// coalescing (52us). R5: DPP scan, all loads up front (41.6us) -> PHASE
// SEPARATION: read drain | compute hump | store drain, bus idles between.
// R6: rolling 3-deep prefetch, compute+store interleaved 1:1 with loads,
// sched_barrier(0x7) pins VMEM issue order so the bus never idles.

#define DT_F  0.1f
#define S_LEN 65536
#define B_ROWS 256
#define CHUNK 2048
#define WARM  1024
#define CPR   (S_LEN / CHUNK)   // 32 chunks per row

typedef float nfloat4 __attribute__((ext_vector_type(4)));

template<int N>
__device__ __forceinline__ float dpp_shr(float x) {
    // lane l receives lane l-N within its 16-lane row; out-of-row lanes get 0.
    return __int_as_float(__builtin_amdgcn_update_dpp(
        0, __float_as_int(x), 0x110 + N, 0xF, 0xF, false));
}
__device__ __forceinline__ float rdl(float x, int l) {
    return __int_as_float(__builtin_amdgcn_readlane(__float_as_int(x), l));
}

__global__ __launch_bounds__(256) void maxwell_scan(
    const float* __restrict__ strain,
    const float* __restrict__ rate,
    const float* __restrict__ log_E,
    const float* __restrict__ log_eta,
    float* __restrict__ out)
{
    const int lane = threadIdx.x & 63;
    const int wid  = blockIdx.x * 4 + (threadIdx.x >> 6);  // 0..8191
    const int row  = wid / CPR;
    const int c    = wid % CPR;

    const float E   = __expf(log_E[0]);
    const float eta = __expf(log_eta[0]);
    const float lam = -DT_F * E / eta;          // ln(a)
    const float a   = __expf(lam);
    const float a2 = a * a, a3 = a2 * a, a4 = a2 * a2, a8 = a4 * a4;
    const float a16 = a8 * a8, a32 = a16 * a16, a64 = a32 * a32;
    const float a128 = a64 * a64, a256 = a128 * a128;
    const float cc = E * (a - 1.0f);
    const float cca1 = cc * a, cca2 = cc * a2, cca3 = cc * a3;

    const int  lrow = lane & 15;
    const float alane = __expf(lam * (float)(4 * lane));   // a^(4*lane)
    const float wX    = __expf(lam * (float)(4 * lrow));   // a^(4*lrow)
    const bool row0 = (lrow == 0);
    const bool ge16 = lane >= 16, ge32 = lane >= 32, ge48 = lane >= 48;

    const int rowbase = row * S_LEN;
    const int t0 = c * CHUNK;
    const nfloat4* s4 = (const nfloat4*)(strain + rowbase);
    nfloat4*       o4 = (nfloat4*)(out + rowbase);
    const int vp = (t0 >> 2) + lane;            // payload group g at vp + 64*g

    const bool has_warm = (c != 0);
    float etar0 = 0.0f;
    if (!has_warm) etar0 = eta * rate[rowbase];  // row-start chunks only

    // ---- warm loads first (needed first), then 3-deep payload prefetch ----
    nfloat4 w0, w1, w2, w3;
    if (has_warm) {
        const int vw = ((t0 - WARM) >> 2) + lane;
        w0 = s4[vw]; w1 = s4[vw + 64]; w2 = s4[vw + 128]; w3 = s4[vw + 192];
    }
    nfloat4 p[8];
    p[0] = s4[vp]; p[1] = s4[vp + 64]; p[2] = s4[vp + 128];
    __builtin_amdgcn_sched_barrier(0x7);   // pin VMEM order; ALU may cross

    float S = 0.0f;   // Z-scan state entering next group

    if (has_warm) {
        auto warmg = [&](nfloat4 wf) {
            float fl = wf.x;
            fl = fmaf(a, fl, wf.y); fl = fmaf(a, fl, wf.z); fl = fmaf(a, fl, wf.w);
            float D = fl, v;
            v = dpp_shr<1>(D); D = fmaf(a4,  v, D);
            v = dpp_shr<2>(D); D = fmaf(a8,  v, D);
            v = dpp_shr<4>(D); D = fmaf(a16, v, D);
            v = dpp_shr<8>(D); D = fmaf(a32, v, D);
            float r15 = rdl(D, 15), r31 = rdl(D, 31), r47 = rdl(D, 47), r63 = rdl(D, 63);
            float P2 = fmaf(a64, r15, r31);
            float P3 = fmaf(a64, P2,  r47);
            float T  = fmaf(a64, P3,  r63);      // group total (256 elems)
            S = fmaf(a256, S, T);
        };
        warmg(w0); warmg(w1); warmg(w2); warmg(w3);
    }

    const float rl0 = etar0 * alane;             // eta*r0 * a^(4*lane)
    const float rl1 = rl0 * a, rl2 = rl0 * a2, rl3 = rl0 * a3;
    float base = 1.0f;                           // a^(256*g) for r0 term

#pragma unroll
    for (int g = 0; g < 8; ++g) {
        // prefetch group g+3 BEFORE stalling on p[g]'s vmcnt
        if (g + 3 < 8) p[g + 3] = s4[vp + 64 * (g + 3)];

        nfloat4 pf = p[g];
        // intra-lane inclusive scan of strain (Z-scan, zero init)
        float fl0 = pf.x;
        float fl1 = fmaf(a, fl0, pf.y);
        float fl2 = fmaf(a, fl1, pf.z);
        float fl3 = fmaf(a, fl2, pf.w);
        // cross-lane weighted scan of lane totals (DPP rows of 16)
        float D = fl3, v;
        v = dpp_shr<1>(D); D = fmaf(a4,  v, D);
        v = dpp_shr<2>(D); D = fmaf(a8,  v, D);
        v = dpp_shr<4>(D); D = fmaf(a16, v, D);
        v = dpp_shr<8>(D); D = fmaf(a32, v, D);
        float r15 = rdl(D, 15), r31 = rdl(D, 31), r47 = rdl(D, 47), r63 = rdl(D, 63);
        float P1 = r15;
        float P2 = fmaf(a64, P1, r31);
        float P3 = fmaf(a64, P2, r47);
        float T  = fmaf(a64, P3, r63);
        // row-prefix for this lane's 16-lane row
        float Pv = ge48 ? P3 : (ge32 ? P2 : (ge16 ? P1 : 0.0f));
        // group-local Z at lane position-1
        float Xd = dpp_shr<1>(D);
        float X  = row0 ? Pv : fmaf(wX, Pv, Xd);
        float Xs = fmaf(alane, S, X);            // + incoming state
        // stress[t] = E*s[t] + c*Z[t-1] + a^t*eta*r0
        nfloat4 o;
        o.x = fmaf(cc,   Xs, E * pf.x);
        o.y = fmaf(cca1, Xs, fmaf(cc, fl0, E * pf.y));
        o.z = fmaf(cca2, Xs, fmaf(cc, fl1, E * pf.z));
        o.w = fmaf(cca3, Xs, fmaf(cc, fl2, E * pf.w));
        o.x = fmaf(base, rl0, o.x);
        o.y = fmaf(base, rl1, o.y);
        o.z = fmaf(base, rl2, o.z);
        o.w = fmaf(base, rl3, o.w);
        o4[vp + g * 64] = o;

        S = fmaf(a256, S, T);
        base *= a256;
        __builtin_amdgcn_sched_barrier(0x7);   // keep load/store 1:1 interleave
    }
}

extern "C" void kernel_launch(void* const* d_in, const int* in_sizes, int n_in,
                              void* d_out, int out_size, void* d_ws, size_t ws_size,
                              hipStream_t stream) {
    const float* strain  = (const float*)d_in[0];
    const float* rate    = (const float*)d_in[1];
    const float* log_E   = (const float*)d_in[2];
    const float* log_eta = (const float*)d_in[3];
    float* out = (float*)d_out;

    const int total_chunks = B_ROWS * CPR;      // 8192 waves
    const int blocks = total_chunks / 4;        // 4 waves / 256-thread block
    maxwell_scan<<<blocks, 256, 0, stream>>>(strain, rate, log_E, log_eta, out);
}